// Round 6
// baseline (567.927 us; speedup 1.0000x reference)
//
#include <hip/hip_runtime.h>
#include <math.h>

#define IN_DIM   128
#define OUT_DIM  128
#define EDGE_DIM 32
#define NUM_HEADS 8
#define HEAD_DIM 16
#define SCALE 0.25f

typedef __attribute__((ext_vector_type(8))) short bf16x8;
typedef __attribute__((ext_vector_type(4))) float f32x4;
typedef __attribute__((ext_vector_type(4))) unsigned int u32x4;

__device__ inline unsigned short f2bf(float x) {   // round-to-nearest-even
    unsigned int u = __float_as_uint(x);
    unsigned int r = u + 0x7fff + ((u >> 16) & 1);
    return (unsigned short)(r >> 16);
}
__device__ inline float bflo(unsigned int u) { return __uint_as_float(u << 16); }
__device__ inline float bfhi(unsigned int u) { return __uint_as_float(u & 0xffff0000u); }

// ---------------------------------------------------------------------------
// prep: fused  [hist over dst] + [W^T bf16 convert] + [We head-sum reduce]
// ---------------------------------------------------------------------------
__global__ __launch_bounds__(256) void prep_kernel(
    const int* __restrict__ el, int* __restrict__ counts, int n_edges, int nbh,
    const float* __restrict__ Wq, const float* __restrict__ Wk,
    const float* __restrict__ Wv, unsigned short* __restrict__ WtB, int nbw,
    const float* __restrict__ We, const float* __restrict__ be,
    float* __restrict__ WeR, float* __restrict__ beR)
{
    const int bx = blockIdx.x;
    const int t  = threadIdx.x;
    if (bx < nbh) {                                   // histogram of dst
        const int e = bx * 256 + t;
        if (e < n_edges) atomicAdd(&counts[((const int2*)el)[e].y], 1);
    } else if (bx < nbh + nbw) {                      // W[k][n] -> WtB[mat][n][k]
        const int idx = (bx - nbh) * 256 + t;
        const int mat = idx >> 14;
        const int rem = idx & 16383;
        const int n = rem >> 7, k = rem & 127;
        const float* W = (mat == 0) ? Wq : (mat == 1) ? Wk : Wv;
        WtB[mat * 16384 + n * 128 + k] = f2bf(W[k * 128 + n]);
    } else {                                          // We reduce
        const int k = t >> 3, h = t & 7;
        float s = 0.f;
#pragma unroll
        for (int d = 0; d < HEAD_DIM; ++d) s += We[k * OUT_DIM + h * HEAD_DIM + d];
        WeR[k * NUM_HEADS + h] = s;
        if (t < NUM_HEADS) {
            float sb = 0.f;
#pragma unroll
            for (int d = 0; d < HEAD_DIM; ++d) sb += be[t * HEAD_DIM + d];
            beR[t] = sb;
        }
    }
}

// ---------------------------------------------------------------------------
// QKV via bf16 MFMA, X converted inline, B-frags from global (L1/L2-hot).
// grid = (ceil(N/64), 3), block = 256 (4 waves, 16 rows each).
// ---------------------------------------------------------------------------
__global__ __launch_bounds__(256) void qkv_mfma_kernel(
    const float* __restrict__ X,
    const unsigned short* __restrict__ WtB,
    const float* __restrict__ bq, const float* __restrict__ bk,
    const float* __restrict__ bv,
    unsigned short* __restrict__ QVb,          // [N][256] = Q|V bf16
    unsigned short* __restrict__ Kb,           // [N][128] bf16
    int n_nodes)
{
    __shared__ unsigned short stg[4][16][136];

    const int t = threadIdx.x;
    const int which = blockIdx.y;
    const float* bias = (which == 0) ? bq : (which == 1) ? bk : bv;
    const unsigned short* Wg = WtB + which * 16384;

    const int wave = t >> 6, lane = t & 63;
    const int quad = lane >> 4, li = lane & 15;
    const int m0 = blockIdx.x * 64 + wave * 16;
    int mrow = m0 + li;
    if (mrow >= n_nodes) mrow = n_nodes - 1;

    f32x4 acc[8];
#pragma unroll
    for (int nt = 0; nt < 8; ++nt) acc[nt] = (f32x4){0.f, 0.f, 0.f, 0.f};

#pragma unroll
    for (int ks = 0; ks < 4; ++ks) {
        const float4* xr = (const float4*)(X + (size_t)mrow * 128 + ks * 32 + quad * 8);
        const float4 x0 = xr[0], x1 = xr[1];
        bf16x8 a;
        a[0] = (short)f2bf(x0.x); a[1] = (short)f2bf(x0.y);
        a[2] = (short)f2bf(x0.z); a[3] = (short)f2bf(x0.w);
        a[4] = (short)f2bf(x1.x); a[5] = (short)f2bf(x1.y);
        a[6] = (short)f2bf(x1.z); a[7] = (short)f2bf(x1.w);
#pragma unroll
        for (int nt = 0; nt < 8; ++nt) {
            const bf16x8 b = *(const bf16x8*)(Wg + (nt * 16 + li) * 128 + ks * 32 + quad * 8);
            acc[nt] = __builtin_amdgcn_mfma_f32_16x16x32_bf16(a, b, acc[nt], 0, 0, 0);
        }
    }

#pragma unroll
    for (int nt = 0; nt < 8; ++nt) {
        const float bb = bias[nt * 16 + li];
#pragma unroll
        for (int r = 0; r < 4; ++r)
            stg[wave][quad * 4 + r][nt * 16 + li] = f2bf(acc[nt][r] + bb);
    }
    __syncthreads();

    {
        const int R = lane >> 2;
        const int c = lane & 3;
        const int node = m0 + R;
        if (node < n_nodes) {
            const u32x4* s = (const u32x4*)(&stg[wave][R][c * 32]);
            u32x4 d0 = s[0], d1 = s[1], d2 = s[2], d3 = s[3];
            unsigned short* dp =
                (which == 0) ? (QVb + (size_t)node * 256 + c * 32)
              : (which == 1) ? (Kb  + (size_t)node * 128 + c * 32)
              :                (QVb + (size_t)node * 256 + 128 + c * 32);
            u32x4* d = (u32x4*)dp;
            d[0] = d0; d[1] = d1; d[2] = d2; d[3] = d3;
        }
    }
}

// ---------------------------------------------------------------------------
// single-block scan over counts (1024 threads; per-thread serial chunk)
// ---------------------------------------------------------------------------
__global__ __launch_bounds__(1024) void scan_kernel(
    const int* __restrict__ counts, int* __restrict__ offsets,
    int* __restrict__ cursor, int n, int n_edges)
{
    __shared__ int lds[1024];
    const int t = threadIdx.x;
    const int c = (n + 1023) >> 10;
    const int base = t * c;
    const int lim  = min(base + c, n);
    int s = 0;
    for (int i = base; i < lim; ++i) s += counts[i];
    lds[t] = s;
    __syncthreads();
    for (int off = 1; off < 1024; off <<= 1) {
        const int v = (t >= off) ? lds[t - off] : 0;
        __syncthreads();
        lds[t] += v;
        __syncthreads();
    }
    int run = (t > 0) ? lds[t - 1] : 0;
    for (int i = base; i < lim; ++i) {
        offsets[i] = run;
        cursor[i]  = run;
        run += counts[i];
    }
    if (t == 1023) offsets[n] = n_edges;
}

// ---------------------------------------------------------------------------
// scatter: one 32B record per edge  [src:4 | pad:4 | ebias bf16 x8:16 | pad:8]
// single cache line touched per edge; non-temporal stores (no RFO).
// ---------------------------------------------------------------------------
__global__ __launch_bounds__(256) void scatter_kernel(
    const int* __restrict__ el, const float* __restrict__ ef,
    const float* __restrict__ WeR, const float* __restrict__ beR,
    int* __restrict__ cursor, unsigned int* __restrict__ recs,  // 8 u32 per edge
    int n_edges)
{
    __shared__ float WeRs[EDGE_DIM * NUM_HEADS];
    __shared__ float beRs[NUM_HEADS];
    const int t = threadIdx.x;
    WeRs[t] = WeR[t];
    if (t < NUM_HEADS) beRs[t] = beR[t];
    __syncthreads();

    const int e = blockIdx.x * 256 + t;
    if (e >= n_edges) return;
    const int2 ed = ((const int2*)el)[e];
    const int src = ed.x, dst = ed.y;

    float acc[NUM_HEADS];
#pragma unroll
    for (int h = 0; h < NUM_HEADS; ++h) acc[h] = beRs[h];

    const f32x4* efr = (const f32x4*)(ef + (size_t)e * EDGE_DIM);
#pragma unroll
    for (int kk = 0; kk < 8; ++kk) {
        const f32x4 f = __builtin_nontemporal_load(efr + kk);
        const float* w0 = &WeRs[(kk * 4 + 0) * NUM_HEADS];
        const float* w1 = &WeRs[(kk * 4 + 1) * NUM_HEADS];
        const float* w2 = &WeRs[(kk * 4 + 2) * NUM_HEADS];
        const float* w3 = &WeRs[(kk * 4 + 3) * NUM_HEADS];
#pragma unroll
        for (int h = 0; h < NUM_HEADS; ++h)
            acc[h] = fmaf(f[0], w0[h], fmaf(f[1], w1[h], fmaf(f[2], w2[h], fmaf(f[3], w3[h], acc[h]))));
    }

    const int pos = atomicAdd(&cursor[dst], 1);
    u32x4 r0, r1;
    r0[0] = (unsigned)src;
    r0[1] = 0;
    r0[2] = (unsigned)f2bf(acc[0]) | ((unsigned)f2bf(acc[1]) << 16);   // heads 0,1
    r0[3] = (unsigned)f2bf(acc[2]) | ((unsigned)f2bf(acc[3]) << 16);   // heads 2,3
    r1[0] = (unsigned)f2bf(acc[4]) | ((unsigned)f2bf(acc[5]) << 16);   // heads 4,5
    r1[1] = (unsigned)f2bf(acc[6]) | ((unsigned)f2bf(acc[7]) << 16);   // heads 6,7
    r1[2] = 0; r1[3] = 0;
    u32x4* rp = (u32x4*)(recs + (size_t)pos * 8);
    __builtin_nontemporal_store(r0, rp);
    __builtin_nontemporal_store(r1, rp + 1);
}

// ---------------------------------------------------------------------------
// aggregate: 2 edges per wave (32 lanes/edge, 4 elems/lane).
// record = 32B: src @ +0, ebias bf16[8] @ +8.
// ---------------------------------------------------------------------------
__global__ __launch_bounds__(256) void aggregate_kernel(
    const unsigned short* __restrict__ QVb, const unsigned short* __restrict__ Kb,
    const int* __restrict__ offsets, const unsigned int* __restrict__ recs,
    float* __restrict__ out, int n_nodes)
{
    const int gw   = (blockIdx.x * 256 + threadIdx.x) >> 6;
    const int lane = threadIdx.x & 63;
    const int half = lane >> 5, ln = lane & 31;
    const int node = gw * 2 + half;
    const int h = ln >> 2;
    const bool valid = node < n_nodes;

    int beg = 0, end = 0;
    if (valid) { beg = offsets[node]; end = offsets[node + 1]; }
    const int cnt = end - beg;
    const int mcnt = max(cnt, __shfl_xor(cnt, 32));

    float k0 = 0.f, k1 = 0.f, k2 = 0.f, k3 = 0.f;
    if (valid) {
        const uint2 kp = ((const uint2*)(Kb + (size_t)node * 128))[ln];
        k0 = bflo(kp.x); k1 = bfhi(kp.x); k2 = bflo(kp.y); k3 = bfhi(kp.y);
    }

    float a0 = 0.f, a1 = 0.f, a2 = 0.f, a3 = 0.f;

    uint2 qp = make_uint2(0, 0), vp = make_uint2(0, 0);
    float eb = 0.f;
    if (cnt > 0) {
        const unsigned int* rb = recs + (size_t)beg * 8;
        const int src = (int)rb[0];
        const unsigned int ebp = rb[2 + (h >> 1)];
        eb = (h & 1) ? bfhi(ebp) : bflo(ebp);
        const uint2* r = (const uint2*)(QVb + (size_t)src * 256);
        qp = r[ln];
        vp = r[32 + ln];
    }

    for (int i = 0; i < mcnt; ++i) {
        uint2 nqp = qp, nvp = vp;
        float neb = eb;
        if (i + 1 < cnt) {   // prefetch next edge (half-uniform branch)
            const unsigned int* rb = recs + (size_t)(beg + i + 1) * 8;
            const int ns = (int)rb[0];
            const unsigned int ebp = rb[2 + (h >> 1)];
            neb = (h & 1) ? bfhi(ebp) : bflo(ebp);
            const uint2* r = (const uint2*)(QVb + (size_t)ns * 256);
            nqp = r[ln];
            nvp = r[32 + ln];
        }

        const float q0 = bflo(qp.x), q1 = bfhi(qp.x);
        const float q2 = bflo(qp.y), q3 = bfhi(qp.y);
        float p = fmaf(q0, k0, fmaf(q1, k1, fmaf(q2, k2, q3 * k3)));
        p += __shfl_xor(p, 1);
        p += __shfl_xor(p, 2);
        const float score = fmaf(p, SCALE, eb);

        float mx = score;
        mx = fmaxf(mx, __shfl_xor(mx, 4));
        mx = fmaxf(mx, __shfl_xor(mx, 8));
        mx = fmaxf(mx, __shfl_xor(mx, 16));
        const float ex = __expf(score - mx);
        float den = ex;
        den += __shfl_xor(den, 4);
        den += __shfl_xor(den, 8);
        den += __shfl_xor(den, 16);
        const float w = __fdividef(ex, den);

        if (i < cnt) {
            a0 = fmaf(w, bflo(vp.x), a0);
            a1 = fmaf(w, bfhi(vp.x), a1);
            a2 = fmaf(w, bflo(vp.y), a2);
            a3 = fmaf(w, bfhi(vp.y), a3);
        }
        qp = nqp; vp = nvp; eb = neb;
    }

    if (valid) {
        f32x4 o; o[0] = a0; o[1] = a1; o[2] = a2; o[3] = a3;
        __builtin_nontemporal_store(o, ((f32x4*)(out + (size_t)node * OUT_DIM)) + ln);
    }
}

// ---------------------------------------------------------------------------
extern "C" void kernel_launch(void* const* d_in, const int* in_sizes, int n_in,
                              void* d_out, int out_size, void* d_ws, size_t ws_size,
                              hipStream_t stream)
{
    const float* X   = (const float*)d_in[0];
    const float* ef  = (const float*)d_in[1];
    const float* Wq  = (const float*)d_in[2];
    const float* bq  = (const float*)d_in[3];
    const float* Wk  = (const float*)d_in[4];
    const float* bk  = (const float*)d_in[5];
    const float* Wv  = (const float*)d_in[6];
    const float* bv  = (const float*)d_in[7];
    const float* We  = (const float*)d_in[8];
    const float* be  = (const float*)d_in[9];
    const int*   el  = (const int*)d_in[10];

    const int n_nodes = in_sizes[0] / IN_DIM;
    const int n_edges = in_sizes[10] / 2;

    char* w = (char*)d_ws;
    auto alloc = [&](size_t bytes) { char* p = w; w += (bytes + 255) & ~(size_t)255; return p; };

    unsigned short* QVb = (unsigned short*)alloc((size_t)n_nodes * 256 * 2);
    unsigned short* Kb  = (unsigned short*)alloc((size_t)n_nodes * 128 * 2);
    unsigned short* WtB = (unsigned short*)alloc((size_t)3 * 128 * 128 * 2);
    unsigned int* recs  = (unsigned int*)alloc((size_t)n_edges * 32);
    float* WeR   = (float*)alloc(EDGE_DIM * NUM_HEADS * 4);
    float* beR   = (float*)alloc(NUM_HEADS * 4);
    int* counts  = (int*)alloc((size_t)n_nodes * 4);
    int* offsets = (int*)alloc((size_t)(n_nodes + 1) * 4);
    int* cursor  = (int*)alloc((size_t)n_nodes * 4);

    (void)hipMemsetAsync(counts, 0, (size_t)n_nodes * sizeof(int), stream);

    const int nbh = (n_edges + 255) / 256;
    const int nbw = (3 * 128 * 128) / 256;
    prep_kernel<<<nbh + nbw + 1, 256, 0, stream>>>(
        el, counts, n_edges, nbh, Wq, Wk, Wv, WtB, nbw, We, be, WeR, beR);

    dim3 qkv_grid((n_nodes + 63) / 64, 3);
    qkv_mfma_kernel<<<qkv_grid, 256, 0, stream>>>(X, WtB, bq, bk, bv, QVb, Kb, n_nodes);

    scan_kernel<<<1, 1024, 0, stream>>>(counts, offsets, cursor, n_nodes, n_edges);

    scatter_kernel<<<(n_edges + 255) / 256, 256, 0, stream>>>(
        el, ef, WeR, beR, cursor, recs, n_edges);

    const int nwaves = (n_nodes + 1) / 2;
    aggregate_kernel<<<(nwaves * 64 + 255) / 256, 256, 0, stream>>>(
        QVb, Kb, offsets, recs, (float*)d_out, n_nodes);
}

// Round 7
// 494.871 us; speedup vs baseline: 1.1476x; 1.1476x over previous
//
#include <hip/hip_runtime.h>
#include <math.h>

#define IN_DIM   128
#define OUT_DIM  128
#define EDGE_DIM 32
#define NUM_HEADS 8
#define HEAD_DIM 16
#define SCALE 0.25f

typedef __attribute__((ext_vector_type(8))) short bf16x8;
typedef __attribute__((ext_vector_type(4))) float f32x4;
typedef __attribute__((ext_vector_type(4))) unsigned int u32x4;

__device__ inline unsigned short f2bf(float x) {   // round-to-nearest-even
    unsigned int u = __float_as_uint(x);
    unsigned int r = u + 0x7fff + ((u >> 16) & 1);
    return (unsigned short)(r >> 16);
}
__device__ inline float bflo(unsigned int u) { return __uint_as_float(u << 16); }
__device__ inline float bfhi(unsigned int u) { return __uint_as_float(u & 0xffff0000u); }

// ---------------------------------------------------------------------------
// reduce_we: We (32x128) -> WeR (32x8) head-sums, be -> beR (8). 1 block.
// ---------------------------------------------------------------------------
__global__ __launch_bounds__(256) void reduce_we_kernel(
    const float* __restrict__ We, const float* __restrict__ be,
    float* __restrict__ WeR, float* __restrict__ beR)
{
    const int t = threadIdx.x;
    const int k = t >> 3, h = t & 7;
    float s = 0.f;
#pragma unroll
    for (int d = 0; d < HEAD_DIM; ++d) s += We[k * OUT_DIM + h * HEAD_DIM + d];
    WeR[k * NUM_HEADS + h] = s;
    if (t < NUM_HEADS) {
        float sb = 0.f;
#pragma unroll
        for (int d = 0; d < HEAD_DIM; ++d) sb += be[t * HEAD_DIM + d];
        beR[t] = sb;
    }
}

// ---------------------------------------------------------------------------
// prep: edge blocks [hist + ebias (streaming, edge order)] + W^T convert blocks
// ---------------------------------------------------------------------------
__global__ __launch_bounds__(256) void prep_kernel(
    const int* __restrict__ el, int* __restrict__ counts,
    const float* __restrict__ ef, const float* __restrict__ WeR,
    const float* __restrict__ beR, unsigned int* __restrict__ ebias_e,  // [E][4] u32 (8 bf16)
    int n_edges, int nbh,
    const float* __restrict__ Wq, const float* __restrict__ Wk,
    const float* __restrict__ Wv, unsigned short* __restrict__ WtB)
{
    const int bx = blockIdx.x;
    const int t  = threadIdx.x;
    if (bx < nbh) {                                   // hist + ebias
        __shared__ float WeRs[EDGE_DIM * NUM_HEADS];
        __shared__ float beRs[NUM_HEADS];
        WeRs[t] = WeR[t];
        if (t < NUM_HEADS) beRs[t] = beR[t];
        __syncthreads();

        const int e = bx * 256 + t;
        if (e >= n_edges) return;
        atomicAdd(&counts[((const int2*)el)[e].y], 1);

        float acc[NUM_HEADS];
#pragma unroll
        for (int h = 0; h < NUM_HEADS; ++h) acc[h] = beRs[h];
        const f32x4* efr = (const f32x4*)(ef + (size_t)e * EDGE_DIM);
#pragma unroll
        for (int kk = 0; kk < 8; ++kk) {
            const f32x4 f = efr[kk];
            const float* w0 = &WeRs[(kk * 4 + 0) * NUM_HEADS];
            const float* w1 = &WeRs[(kk * 4 + 1) * NUM_HEADS];
            const float* w2 = &WeRs[(kk * 4 + 2) * NUM_HEADS];
            const float* w3 = &WeRs[(kk * 4 + 3) * NUM_HEADS];
#pragma unroll
            for (int h = 0; h < NUM_HEADS; ++h)
                acc[h] = fmaf(f[0], w0[h], fmaf(f[1], w1[h], fmaf(f[2], w2[h], fmaf(f[3], w3[h], acc[h]))));
        }
        u32x4 pk;
        pk[0] = (unsigned)f2bf(acc[0]) | ((unsigned)f2bf(acc[1]) << 16);
        pk[1] = (unsigned)f2bf(acc[2]) | ((unsigned)f2bf(acc[3]) << 16);
        pk[2] = (unsigned)f2bf(acc[4]) | ((unsigned)f2bf(acc[5]) << 16);
        pk[3] = (unsigned)f2bf(acc[6]) | ((unsigned)f2bf(acc[7]) << 16);
        *(u32x4*)(ebias_e + (size_t)e * 4) = pk;
    } else {                                          // W[k][n] -> WtB[mat][n][k]
        const int idx = (bx - nbh) * 256 + t;
        if (idx >= 3 * 128 * 128) return;
        const int mat = idx >> 14;
        const int rem = idx & 16383;
        const int n = rem >> 7, k = rem & 127;
        const float* W = (mat == 0) ? Wq : (mat == 1) ? Wk : Wv;
        WtB[mat * 16384 + n * 128 + k] = f2bf(W[k * 128 + n]);
    }
}

// ---------------------------------------------------------------------------
// QKV via bf16 MFMA, X converted inline, B-frags from global (L1/L2-hot).
// grid = (ceil(N/64), 3), block = 256 (4 waves, 16 rows each).
// ---------------------------------------------------------------------------
__global__ __launch_bounds__(256) void qkv_mfma_kernel(
    const float* __restrict__ X,
    const unsigned short* __restrict__ WtB,
    const float* __restrict__ bq, const float* __restrict__ bk,
    const float* __restrict__ bv,
    unsigned short* __restrict__ QVb,          // [N][256] = Q|V bf16
    unsigned short* __restrict__ Kb,           // [N][128] bf16
    int n_nodes)
{
    __shared__ unsigned short stg[4][16][136];

    const int t = threadIdx.x;
    const int which = blockIdx.y;
    const float* bias = (which == 0) ? bq : (which == 1) ? bk : bv;
    const unsigned short* Wg = WtB + which * 16384;

    const int wave = t >> 6, lane = t & 63;
    const int quad = lane >> 4, li = lane & 15;
    const int m0 = blockIdx.x * 64 + wave * 16;
    int mrow = m0 + li;
    if (mrow >= n_nodes) mrow = n_nodes - 1;

    f32x4 acc[8];
#pragma unroll
    for (int nt = 0; nt < 8; ++nt) acc[nt] = (f32x4){0.f, 0.f, 0.f, 0.f};

#pragma unroll
    for (int ks = 0; ks < 4; ++ks) {
        const f32x4* xr = (const f32x4*)(X + (size_t)mrow * 128 + ks * 32 + quad * 8);
        const f32x4 x0 = xr[0], x1 = xr[1];
        bf16x8 a;
        a[0] = (short)f2bf(x0[0]); a[1] = (short)f2bf(x0[1]);
        a[2] = (short)f2bf(x0[2]); a[3] = (short)f2bf(x0[3]);
        a[4] = (short)f2bf(x1[0]); a[5] = (short)f2bf(x1[1]);
        a[6] = (short)f2bf(x1[2]); a[7] = (short)f2bf(x1[3]);
#pragma unroll
        for (int nt = 0; nt < 8; ++nt) {
            const bf16x8 b = *(const bf16x8*)(Wg + (nt * 16 + li) * 128 + ks * 32 + quad * 8);
            acc[nt] = __builtin_amdgcn_mfma_f32_16x16x32_bf16(a, b, acc[nt], 0, 0, 0);
        }
    }

#pragma unroll
    for (int nt = 0; nt < 8; ++nt) {
        const float bb = bias[nt * 16 + li];
#pragma unroll
        for (int r = 0; r < 4; ++r)
            stg[wave][quad * 4 + r][nt * 16 + li] = f2bf(acc[nt][r] + bb);
    }
    __syncthreads();

    {
        const int R = lane >> 2;
        const int c = lane & 3;
        const int node = m0 + R;
        if (node < n_nodes) {
            const u32x4* s = (const u32x4*)(&stg[wave][R][c * 32]);
            u32x4 d0 = s[0], d1 = s[1], d2 = s[2], d3 = s[3];
            unsigned short* dp =
                (which == 0) ? (QVb + (size_t)node * 256 + c * 32)
              : (which == 1) ? (Kb  + (size_t)node * 128 + c * 32)
              :                (QVb + (size_t)node * 256 + 128 + c * 32);
            u32x4* d = (u32x4*)dp;
            d[0] = d0; d[1] = d1; d[2] = d2; d[3] = d3;
        }
    }
}

// ---------------------------------------------------------------------------
// single-block scan over counts (1024 threads; per-thread serial chunk)
// ---------------------------------------------------------------------------
__global__ __launch_bounds__(1024) void scan_kernel(
    const int* __restrict__ counts, int* __restrict__ offsets,
    int* __restrict__ cursor, int n, int n_edges)
{
    __shared__ int lds[1024];
    const int t = threadIdx.x;
    const int c = (n + 1023) >> 10;
    const int base = t * c;
    const int lim  = min(base + c, n);
    int s = 0;
    for (int i = base; i < lim; ++i) s += counts[i];
    lds[t] = s;
    __syncthreads();
    for (int off = 1; off < 1024; off <<= 1) {
        const int v = (t >= off) ? lds[t - off] : 0;
        __syncthreads();
        lds[t] += v;
        __syncthreads();
    }
    int run = (t > 0) ? lds[t - 1] : 0;
    for (int i = base; i < lim; ++i) {
        offsets[i] = run;
        cursor[i]  = run;
        run += counts[i];
    }
    if (t == 1023) offsets[n] = n_edges;
}

// ---------------------------------------------------------------------------
// scatter: pure permutation. Read el + ebias_e (streaming), write one 32B
// record per edge  [src:4 | pad:4 | ebias bf16 x8:16 | pad:8]  (regular stores
// -> L2 merges; single cache line touched per edge).
// ---------------------------------------------------------------------------
__global__ __launch_bounds__(256) void scatter_kernel(
    const int* __restrict__ el, const unsigned int* __restrict__ ebias_e,
    int* __restrict__ cursor, unsigned int* __restrict__ recs,  // 8 u32 per edge
    int n_edges)
{
    const int e = blockIdx.x * 256 + threadIdx.x;
    if (e >= n_edges) return;
    const int2 ed = ((const int2*)el)[e];
    const u32x4 eb = *(const u32x4*)(ebias_e + (size_t)e * 4);

    const int pos = atomicAdd(&cursor[ed.y], 1);
    u32x4 r0, r1;
    r0[0] = (unsigned)ed.x;
    r0[1] = 0;
    r0[2] = eb[0];
    r0[3] = eb[1];
    r1[0] = eb[2];
    r1[1] = eb[3];
    r1[2] = 0; r1[3] = 0;
    u32x4* rp = (u32x4*)(recs + (size_t)pos * 8);
    rp[0] = r0;
    rp[1] = r1;
}

// ---------------------------------------------------------------------------
// aggregate: 2 edges per wave (32 lanes/edge, 4 elems/lane).
// record = 32B: src @ +0, ebias bf16[8] @ +8.
// ---------------------------------------------------------------------------
__global__ __launch_bounds__(256) void aggregate_kernel(
    const unsigned short* __restrict__ QVb, const unsigned short* __restrict__ Kb,
    const int* __restrict__ offsets, const unsigned int* __restrict__ recs,
    float* __restrict__ out, int n_nodes)
{
    const int gw   = (blockIdx.x * 256 + threadIdx.x) >> 6;
    const int lane = threadIdx.x & 63;
    const int half = lane >> 5, ln = lane & 31;
    const int node = gw * 2 + half;
    const int h = ln >> 2;
    const bool valid = node < n_nodes;

    int beg = 0, end = 0;
    if (valid) { beg = offsets[node]; end = offsets[node + 1]; }
    const int cnt = end - beg;
    const int mcnt = max(cnt, __shfl_xor(cnt, 32));

    float k0 = 0.f, k1 = 0.f, k2 = 0.f, k3 = 0.f;
    if (valid) {
        const uint2 kp = ((const uint2*)(Kb + (size_t)node * 128))[ln];
        k0 = bflo(kp.x); k1 = bfhi(kp.x); k2 = bflo(kp.y); k3 = bfhi(kp.y);
    }

    float a0 = 0.f, a1 = 0.f, a2 = 0.f, a3 = 0.f;

    uint2 qp = make_uint2(0, 0), vp = make_uint2(0, 0);
    float eb = 0.f;
    if (cnt > 0) {
        const unsigned int* rb = recs + (size_t)beg * 8;
        const int src = (int)rb[0];
        const unsigned int ebp = rb[2 + (h >> 1)];
        eb = (h & 1) ? bfhi(ebp) : bflo(ebp);
        const uint2* r = (const uint2*)(QVb + (size_t)src * 256);
        qp = r[ln];
        vp = r[32 + ln];
    }

    for (int i = 0; i < mcnt; ++i) {
        uint2 nqp = qp, nvp = vp;
        float neb = eb;
        if (i + 1 < cnt) {   // prefetch next edge (half-uniform branch)
            const unsigned int* rb = recs + (size_t)(beg + i + 1) * 8;
            const int ns = (int)rb[0];
            const unsigned int ebp = rb[2 + (h >> 1)];
            neb = (h & 1) ? bfhi(ebp) : bflo(ebp);
            const uint2* r = (const uint2*)(QVb + (size_t)ns * 256);
            nqp = r[ln];
            nvp = r[32 + ln];
        }

        const float q0 = bflo(qp.x), q1 = bfhi(qp.x);
        const float q2 = bflo(qp.y), q3 = bfhi(qp.y);
        float p = fmaf(q0, k0, fmaf(q1, k1, fmaf(q2, k2, q3 * k3)));
        p += __shfl_xor(p, 1);
        p += __shfl_xor(p, 2);
        const float score = fmaf(p, SCALE, eb);

        float mx = score;
        mx = fmaxf(mx, __shfl_xor(mx, 4));
        mx = fmaxf(mx, __shfl_xor(mx, 8));
        mx = fmaxf(mx, __shfl_xor(mx, 16));
        const float ex = __expf(score - mx);
        float den = ex;
        den += __shfl_xor(den, 4);
        den += __shfl_xor(den, 8);
        den += __shfl_xor(den, 16);
        const float w = __fdividef(ex, den);

        if (i < cnt) {
            a0 = fmaf(w, bflo(vp.x), a0);
            a1 = fmaf(w, bfhi(vp.x), a1);
            a2 = fmaf(w, bflo(vp.y), a2);
            a3 = fmaf(w, bfhi(vp.y), a3);
        }
        qp = nqp; vp = nvp; eb = neb;
    }

    if (valid) {
        f32x4 o; o[0] = a0; o[1] = a1; o[2] = a2; o[3] = a3;
        *(((f32x4*)(out + (size_t)node * OUT_DIM)) + ln) = o;
    }
}

// ---------------------------------------------------------------------------
extern "C" void kernel_launch(void* const* d_in, const int* in_sizes, int n_in,
                              void* d_out, int out_size, void* d_ws, size_t ws_size,
                              hipStream_t stream)
{
    const float* X   = (const float*)d_in[0];
    const float* ef  = (const float*)d_in[1];
    const float* Wq  = (const float*)d_in[2];
    const float* bq  = (const float*)d_in[3];
    const float* Wk  = (const float*)d_in[4];
    const float* bk  = (const float*)d_in[5];
    const float* Wv  = (const float*)d_in[6];
    const float* bv  = (const float*)d_in[7];
    const float* We  = (const float*)d_in[8];
    const float* be  = (const float*)d_in[9];
    const int*   el  = (const int*)d_in[10];

    const int n_nodes = in_sizes[0] / IN_DIM;
    const int n_edges = in_sizes[10] / 2;

    char* w = (char*)d_ws;
    auto alloc = [&](size_t bytes) { char* p = w; w += (bytes + 255) & ~(size_t)255; return p; };

    unsigned short* QVb    = (unsigned short*)alloc((size_t)n_nodes * 256 * 2);
    unsigned short* Kb     = (unsigned short*)alloc((size_t)n_nodes * 128 * 2);
    unsigned short* WtB    = (unsigned short*)alloc((size_t)3 * 128 * 128 * 2);
    unsigned int*   recs   = (unsigned int*)alloc((size_t)n_edges * 32);
    unsigned int*   ebias_e= (unsigned int*)alloc((size_t)n_edges * 16);
    float* WeR   = (float*)alloc(EDGE_DIM * NUM_HEADS * 4);
    float* beR   = (float*)alloc(NUM_HEADS * 4);
    int* counts  = (int*)alloc((size_t)n_nodes * 4);
    int* offsets = (int*)alloc((size_t)(n_nodes + 1) * 4);
    int* cursor  = (int*)alloc((size_t)n_nodes * 4);

    (void)hipMemsetAsync(counts, 0, (size_t)n_nodes * sizeof(int), stream);

    reduce_we_kernel<<<1, 256, 0, stream>>>(We, be, WeR, beR);

    const int nbh = (n_edges + 255) / 256;
    const int nbw = (3 * 128 * 128) / 256;
    prep_kernel<<<nbh + nbw, 256, 0, stream>>>(
        el, counts, ef, WeR, beR, ebias_e, n_edges, nbh, Wq, Wk, Wv, WtB);

    dim3 qkv_grid((n_nodes + 63) / 64, 3);
    qkv_mfma_kernel<<<qkv_grid, 256, 0, stream>>>(X, WtB, bq, bk, bv, QVb, Kb, n_nodes);

    scan_kernel<<<1, 1024, 0, stream>>>(counts, offsets, cursor, n_nodes, n_edges);

    scatter_kernel<<<(n_edges + 255) / 256, 256, 0, stream>>>(
        el, ebias_e, cursor, recs, n_edges);

    const int nwaves = (n_nodes + 1) / 2;
    aggregate_kernel<<<(nwaves * 64 + 255) / 256, 256, 0, stream>>>(
        QVb, Kb, offsets, recs, (float*)d_out, n_nodes);
}

// Round 8
// 392.312 us; speedup vs baseline: 1.4476x; 1.2614x over previous
//
#include <hip/hip_runtime.h>
#include <math.h>

#define IN_DIM   128
#define OUT_DIM  128
#define EDGE_DIM 32
#define NUM_HEADS 8
#define HEAD_DIM 16
#define SCALE 0.25f

typedef __attribute__((ext_vector_type(8))) short bf16x8;
typedef __attribute__((ext_vector_type(4))) float f32x4;
typedef __attribute__((ext_vector_type(4))) unsigned int u32x4;

__device__ inline unsigned short f2bf(float x) {   // round-to-nearest-even
    unsigned int u = __float_as_uint(x);
    unsigned int r = u + 0x7fff + ((u >> 16) & 1);
    return (unsigned short)(r >> 16);
}
__device__ inline float bflo(unsigned int u) { return __uint_as_float(u << 16); }
__device__ inline float bfhi(unsigned int u) { return __uint_as_float(u & 0xffff0000u); }

// ---------------------------------------------------------------------------
// reduce_we: We (32x128) -> WeR (32x8) head-sums, be -> beR (8). 1 block.
// ---------------------------------------------------------------------------
__global__ __launch_bounds__(256) void reduce_we_kernel(
    const float* __restrict__ We, const float* __restrict__ be,
    float* __restrict__ WeR, float* __restrict__ beR)
{
    const int t = threadIdx.x;
    const int k = t >> 3, h = t & 7;
    float s = 0.f;
#pragma unroll
    for (int d = 0; d < HEAD_DIM; ++d) s += We[k * OUT_DIM + h * HEAD_DIM + d];
    WeR[k * NUM_HEADS + h] = s;
    if (t < NUM_HEADS) {
        float sb = 0.f;
#pragma unroll
        for (int d = 0; d < HEAD_DIM; ++d) sb += be[t * HEAD_DIM + d];
        beR[t] = sb;
    }
}

// ---------------------------------------------------------------------------
// prep: edge blocks [hist + ebias (streaming, edge order)] + W^T convert blocks
// ---------------------------------------------------------------------------
__global__ __launch_bounds__(256) void prep_kernel(
    const int* __restrict__ el, int* __restrict__ counts,
    const float* __restrict__ ef, const float* __restrict__ WeR,
    const float* __restrict__ beR, unsigned int* __restrict__ ebias_e,  // [E][4] u32 (8 bf16)
    int n_edges, int nbh,
    const float* __restrict__ Wq, const float* __restrict__ Wk,
    const float* __restrict__ Wv, unsigned short* __restrict__ WtB)
{
    const int bx = blockIdx.x;
    const int t  = threadIdx.x;
    if (bx < nbh) {                                   // hist + ebias
        __shared__ float WeRs[EDGE_DIM * NUM_HEADS];
        __shared__ float beRs[NUM_HEADS];
        WeRs[t] = WeR[t];
        if (t < NUM_HEADS) beRs[t] = beR[t];
        __syncthreads();

        const int e = bx * 256 + t;
        if (e >= n_edges) return;
        atomicAdd(&counts[((const int2*)el)[e].y], 1);

        float acc[NUM_HEADS];
#pragma unroll
        for (int h = 0; h < NUM_HEADS; ++h) acc[h] = beRs[h];
        const f32x4* efr = (const f32x4*)(ef + (size_t)e * EDGE_DIM);
#pragma unroll
        for (int kk = 0; kk < 8; ++kk) {
            const f32x4 f = efr[kk];
            const float* w0 = &WeRs[(kk * 4 + 0) * NUM_HEADS];
            const float* w1 = &WeRs[(kk * 4 + 1) * NUM_HEADS];
            const float* w2 = &WeRs[(kk * 4 + 2) * NUM_HEADS];
            const float* w3 = &WeRs[(kk * 4 + 3) * NUM_HEADS];
#pragma unroll
            for (int h = 0; h < NUM_HEADS; ++h)
                acc[h] = fmaf(f[0], w0[h], fmaf(f[1], w1[h], fmaf(f[2], w2[h], fmaf(f[3], w3[h], acc[h]))));
        }
        u32x4 pk;
        pk[0] = (unsigned)f2bf(acc[0]) | ((unsigned)f2bf(acc[1]) << 16);
        pk[1] = (unsigned)f2bf(acc[2]) | ((unsigned)f2bf(acc[3]) << 16);
        pk[2] = (unsigned)f2bf(acc[4]) | ((unsigned)f2bf(acc[5]) << 16);
        pk[3] = (unsigned)f2bf(acc[6]) | ((unsigned)f2bf(acc[7]) << 16);
        *(u32x4*)(ebias_e + (size_t)e * 4) = pk;
    } else {                                          // W[k][n] -> WtB[mat][n][k]
        const int idx = (bx - nbh) * 256 + t;
        if (idx >= 3 * 128 * 128) return;
        const int mat = idx >> 14;
        const int rem = idx & 16383;
        const int n = rem >> 7, k = rem & 127;
        const float* W = (mat == 0) ? Wq : (mat == 1) ? Wk : Wv;
        WtB[mat * 16384 + n * 128 + k] = f2bf(W[k * 128 + n]);
    }
}

// ---------------------------------------------------------------------------
// QKV via bf16 MFMA, X converted inline, B-frags from global (L1/L2-hot).
// grid = (ceil(N/64), 3), block = 256 (4 waves, 16 rows each).
// ---------------------------------------------------------------------------
__global__ __launch_bounds__(256) void qkv_mfma_kernel(
    const float* __restrict__ X,
    const unsigned short* __restrict__ WtB,
    const float* __restrict__ bq, const float* __restrict__ bk,
    const float* __restrict__ bv,
    unsigned short* __restrict__ QVb,          // [N][256] = Q|V bf16
    unsigned short* __restrict__ Kb,           // [N][128] bf16
    int n_nodes)
{
    __shared__ unsigned short stg[4][16][136];

    const int t = threadIdx.x;
    const int which = blockIdx.y;
    const float* bias = (which == 0) ? bq : (which == 1) ? bk : bv;
    const unsigned short* Wg = WtB + which * 16384;

    const int wave = t >> 6, lane = t & 63;
    const int quad = lane >> 4, li = lane & 15;
    const int m0 = blockIdx.x * 64 + wave * 16;
    int mrow = m0 + li;
    if (mrow >= n_nodes) mrow = n_nodes - 1;

    f32x4 acc[8];
#pragma unroll
    for (int nt = 0; nt < 8; ++nt) acc[nt] = (f32x4){0.f, 0.f, 0.f, 0.f};

#pragma unroll
    for (int ks = 0; ks < 4; ++ks) {
        const f32x4* xr = (const f32x4*)(X + (size_t)mrow * 128 + ks * 32 + quad * 8);
        const f32x4 x0 = xr[0], x1 = xr[1];
        bf16x8 a;
        a[0] = (short)f2bf(x0[0]); a[1] = (short)f2bf(x0[1]);
        a[2] = (short)f2bf(x0[2]); a[3] = (short)f2bf(x0[3]);
        a[4] = (short)f2bf(x1[0]); a[5] = (short)f2bf(x1[1]);
        a[6] = (short)f2bf(x1[2]); a[7] = (short)f2bf(x1[3]);
#pragma unroll
        for (int nt = 0; nt < 8; ++nt) {
            const bf16x8 b = *(const bf16x8*)(Wg + (nt * 16 + li) * 128 + ks * 32 + quad * 8);
            acc[nt] = __builtin_amdgcn_mfma_f32_16x16x32_bf16(a, b, acc[nt], 0, 0, 0);
        }
    }

#pragma unroll
    for (int nt = 0; nt < 8; ++nt) {
        const float bb = bias[nt * 16 + li];
#pragma unroll
        for (int r = 0; r < 4; ++r)
            stg[wave][quad * 4 + r][nt * 16 + li] = f2bf(acc[nt][r] + bb);
    }
    __syncthreads();

    {
        const int R = lane >> 2;
        const int c = lane & 3;
        const int node = m0 + R;
        if (node < n_nodes) {
            const u32x4* s = (const u32x4*)(&stg[wave][R][c * 32]);
            u32x4 d0 = s[0], d1 = s[1], d2 = s[2], d3 = s[3];
            unsigned short* dp =
                (which == 0) ? (QVb + (size_t)node * 256 + c * 32)
              : (which == 1) ? (Kb  + (size_t)node * 128 + c * 32)
              :                (QVb + (size_t)node * 256 + 128 + c * 32);
            u32x4* d = (u32x4*)dp;
            d[0] = d0; d[1] = d1; d[2] = d2; d[3] = d3;
        }
    }
}

// ---------------------------------------------------------------------------
// 3-phase coalesced scan (single-block serial scan was 111 us: per-thread
// chunks make every wave access 64 distinct lines -> latency serialization)
// ---------------------------------------------------------------------------
__global__ __launch_bounds__(256) void scan1_kernel(
    const int* __restrict__ counts, int* __restrict__ bsums, int n)
{
    __shared__ int lds[256];
    const int i = blockIdx.x * 256 + threadIdx.x;
    lds[threadIdx.x] = (i < n) ? counts[i] : 0;
    __syncthreads();
    for (int off = 128; off > 0; off >>= 1) {
        if (threadIdx.x < off) lds[threadIdx.x] += lds[threadIdx.x + off];
        __syncthreads();
    }
    if (threadIdx.x == 0) bsums[blockIdx.x] = lds[0];
}

__global__ __launch_bounds__(256) void scan2_kernel(int* __restrict__ bsums, int nb)
{
    __shared__ int lds[256];
    const int t = threadIdx.x;
    const int v = (t < nb) ? bsums[t] : 0;
    lds[t] = v;
    __syncthreads();
    for (int off = 1; off < 256; off <<= 1) {
        const int u = (t >= off) ? lds[t - off] : 0;
        __syncthreads();
        lds[t] += u;
        __syncthreads();
    }
    if (t < nb) bsums[t] = lds[t] - v;   // exclusive
}

__global__ __launch_bounds__(256) void scan3_kernel(
    const int* __restrict__ counts, const int* __restrict__ bsums,
    int* __restrict__ offsets, int* __restrict__ cursor, int n, int n_edges)
{
    __shared__ int lds[256];
    const int t = threadIdx.x;
    const int i = blockIdx.x * 256 + t;
    const int v = (i < n) ? counts[i] : 0;
    lds[t] = v;
    __syncthreads();
    for (int off = 1; off < 256; off <<= 1) {
        const int u = (t >= off) ? lds[t - off] : 0;
        __syncthreads();
        lds[t] += u;
        __syncthreads();
    }
    if (i < n) {
        const int excl = bsums[blockIdx.x] + lds[t] - v;
        offsets[i] = excl;
        cursor[i]  = excl;
    }
    if (blockIdx.x == 0 && t == 0) offsets[n] = n_edges;
}

// ---------------------------------------------------------------------------
// scatter: pure permutation. Read el + ebias_e (streaming), write one 32B
// record per edge  [src:4 | pad:4 | ebias bf16 x8:16 | pad:8].
// ---------------------------------------------------------------------------
__global__ __launch_bounds__(256) void scatter_kernel(
    const int* __restrict__ el, const unsigned int* __restrict__ ebias_e,
    int* __restrict__ cursor, unsigned int* __restrict__ recs,  // 8 u32 per edge
    int n_edges)
{
    const int e = blockIdx.x * 256 + threadIdx.x;
    if (e >= n_edges) return;
    const int2 ed = ((const int2*)el)[e];
    const u32x4 eb = *(const u32x4*)(ebias_e + (size_t)e * 4);

    const int pos = atomicAdd(&cursor[ed.y], 1);
    u32x4 r0, r1;
    r0[0] = (unsigned)ed.x;
    r0[1] = 0;
    r0[2] = eb[0];
    r0[3] = eb[1];
    r1[0] = eb[2];
    r1[1] = eb[3];
    r1[2] = 0; r1[3] = 0;
    u32x4* rp = (u32x4*)(recs + (size_t)pos * 8);
    rp[0] = r0;
    rp[1] = r1;
}

// ---------------------------------------------------------------------------
// aggregate: 2 edges per wave (32 lanes/edge, 4 elems/lane).
// record = 32B: src @ +0, ebias bf16[8] @ +8.
// ---------------------------------------------------------------------------
__global__ __launch_bounds__(256) void aggregate_kernel(
    const unsigned short* __restrict__ QVb, const unsigned short* __restrict__ Kb,
    const int* __restrict__ offsets, const unsigned int* __restrict__ recs,
    float* __restrict__ out, int n_nodes)
{
    const int gw   = (blockIdx.x * 256 + threadIdx.x) >> 6;
    const int lane = threadIdx.x & 63;
    const int half = lane >> 5, ln = lane & 31;
    const int node = gw * 2 + half;
    const int h = ln >> 2;
    const bool valid = node < n_nodes;

    int beg = 0, end = 0;
    if (valid) { beg = offsets[node]; end = offsets[node + 1]; }
    const int cnt = end - beg;
    const int mcnt = max(cnt, __shfl_xor(cnt, 32));

    float k0 = 0.f, k1 = 0.f, k2 = 0.f, k3 = 0.f;
    if (valid) {
        const uint2 kp = ((const uint2*)(Kb + (size_t)node * 128))[ln];
        k0 = bflo(kp.x); k1 = bfhi(kp.x); k2 = bflo(kp.y); k3 = bfhi(kp.y);
    }

    float a0 = 0.f, a1 = 0.f, a2 = 0.f, a3 = 0.f;

    uint2 qp = make_uint2(0, 0), vp = make_uint2(0, 0);
    float eb = 0.f;
    if (cnt > 0) {
        const unsigned int* rb = recs + (size_t)beg * 8;
        const int src = (int)rb[0];
        const unsigned int ebp = rb[2 + (h >> 1)];
        eb = (h & 1) ? bfhi(ebp) : bflo(ebp);
        const uint2* r = (const uint2*)(QVb + (size_t)src * 256);
        qp = r[ln];
        vp = r[32 + ln];
    }

    for (int i = 0; i < mcnt; ++i) {
        uint2 nqp = qp, nvp = vp;
        float neb = eb;
        if (i + 1 < cnt) {   // prefetch next edge (half-uniform branch)
            const unsigned int* rb = recs + (size_t)(beg + i + 1) * 8;
            const int ns = (int)rb[0];
            const unsigned int ebp = rb[2 + (h >> 1)];
            neb = (h & 1) ? bfhi(ebp) : bflo(ebp);
            const uint2* r = (const uint2*)(QVb + (size_t)ns * 256);
            nqp = r[ln];
            nvp = r[32 + ln];
        }

        const float q0 = bflo(qp.x), q1 = bfhi(qp.x);
        const float q2 = bflo(qp.y), q3 = bfhi(qp.y);
        float p = fmaf(q0, k0, fmaf(q1, k1, fmaf(q2, k2, q3 * k3)));
        p += __shfl_xor(p, 1);
        p += __shfl_xor(p, 2);
        const float score = fmaf(p, SCALE, eb);

        float mx = score;
        mx = fmaxf(mx, __shfl_xor(mx, 4));
        mx = fmaxf(mx, __shfl_xor(mx, 8));
        mx = fmaxf(mx, __shfl_xor(mx, 16));
        const float ex = __expf(score - mx);
        float den = ex;
        den += __shfl_xor(den, 4);
        den += __shfl_xor(den, 8);
        den += __shfl_xor(den, 16);
        const float w = __fdividef(ex, den);

        if (i < cnt) {
            a0 = fmaf(w, bflo(vp.x), a0);
            a1 = fmaf(w, bfhi(vp.x), a1);
            a2 = fmaf(w, bflo(vp.y), a2);
            a3 = fmaf(w, bfhi(vp.y), a3);
        }
        qp = nqp; vp = nvp; eb = neb;
    }

    if (valid) {
        f32x4 o; o[0] = a0; o[1] = a1; o[2] = a2; o[3] = a3;
        *(((f32x4*)(out + (size_t)node * OUT_DIM)) + ln) = o;
    }
}

// ---------------------------------------------------------------------------
extern "C" void kernel_launch(void* const* d_in, const int* in_sizes, int n_in,
                              void* d_out, int out_size, void* d_ws, size_t ws_size,
                              hipStream_t stream)
{
    const float* X   = (const float*)d_in[0];
    const float* ef  = (const float*)d_in[1];
    const float* Wq  = (const float*)d_in[2];
    const float* bq  = (const float*)d_in[3];
    const float* Wk  = (const float*)d_in[4];
    const float* bk  = (const float*)d_in[5];
    const float* Wv  = (const float*)d_in[6];
    const float* bv  = (const float*)d_in[7];
    const float* We  = (const float*)d_in[8];
    const float* be  = (const float*)d_in[9];
    const int*   el  = (const int*)d_in[10];

    const int n_nodes = in_sizes[0] / IN_DIM;
    const int n_edges = in_sizes[10] / 2;

    char* w = (char*)d_ws;
    auto alloc = [&](size_t bytes) { char* p = w; w += (bytes + 255) & ~(size_t)255; return p; };

    unsigned short* QVb    = (unsigned short*)alloc((size_t)n_nodes * 256 * 2);
    unsigned short* Kb     = (unsigned short*)alloc((size_t)n_nodes * 128 * 2);
    unsigned short* WtB    = (unsigned short*)alloc((size_t)3 * 128 * 128 * 2);
    unsigned int*   recs   = (unsigned int*)alloc((size_t)n_edges * 32);
    unsigned int*   ebias_e= (unsigned int*)alloc((size_t)n_edges * 16);
    float* WeR   = (float*)alloc(EDGE_DIM * NUM_HEADS * 4);
    float* beR   = (float*)alloc(NUM_HEADS * 4);
    int* counts  = (int*)alloc((size_t)n_nodes * 4);
    int* offsets = (int*)alloc((size_t)(n_nodes + 1) * 4);
    int* cursor  = (int*)alloc((size_t)n_nodes * 4);
    int* bsums   = (int*)alloc(256 * 4);

    (void)hipMemsetAsync(counts, 0, (size_t)n_nodes * sizeof(int), stream);

    reduce_we_kernel<<<1, 256, 0, stream>>>(We, be, WeR, beR);

    const int nbh = (n_edges + 255) / 256;
    const int nbw = (3 * 128 * 128) / 256;
    prep_kernel<<<nbh + nbw, 256, 0, stream>>>(
        el, counts, ef, WeR, beR, ebias_e, n_edges, nbh, Wq, Wk, Wv, WtB);

    dim3 qkv_grid((n_nodes + 63) / 64, 3);
    qkv_mfma_kernel<<<qkv_grid, 256, 0, stream>>>(X, WtB, bq, bk, bv, QVb, Kb, n_nodes);

    const int nb = (n_nodes + 255) / 256;
    scan1_kernel<<<nb, 256, 0, stream>>>(counts, bsums, n_nodes);
    scan2_kernel<<<1, 256, 0, stream>>>(bsums, nb);
    scan3_kernel<<<nb, 256, 0, stream>>>(counts, bsums, offsets, cursor, n_nodes, n_edges);

    scatter_kernel<<<(n_edges + 255) / 256, 256, 0, stream>>>(
        el, ebias_e, cursor, recs, n_edges);

    const int nwaves = (n_nodes + 1) / 2;
    aggregate_kernel<<<(nwaves * 64 + 255) / 256, 256, 0, stream>>>(
        QVb, Kb, offsets, recs, (float*)d_out, n_nodes);
}

// Round 9
// 347.526 us; speedup vs baseline: 1.6342x; 1.1289x over previous
//
#include <hip/hip_runtime.h>
#include <math.h>

#define IN_DIM   128
#define OUT_DIM  128
#define EDGE_DIM 32
#define NUM_HEADS 8
#define HEAD_DIM 16
#define SCALE 0.25f

typedef __attribute__((ext_vector_type(8))) short bf16x8;
typedef __attribute__((ext_vector_type(4))) float f32x4;
typedef __attribute__((ext_vector_type(4))) unsigned int u32x4;

__device__ inline unsigned short f2bf(float x) {   // round-to-nearest-even
    unsigned int u = __float_as_uint(x);
    unsigned int r = u + 0x7fff + ((u >> 16) & 1);
    return (unsigned short)(r >> 16);
}
__device__ inline float bflo(unsigned int u) { return __uint_as_float(u << 16); }
__device__ inline float bfhi(unsigned int u) { return __uint_as_float(u & 0xffff0000u); }

// ---------------------------------------------------------------------------
// setup: [zero counts] + [W^T bf16 convert] + [We head-sum reduce], one launch
// grid = nbz + nbw + 1
// ---------------------------------------------------------------------------
__global__ __launch_bounds__(256) void setup_kernel(
    int* __restrict__ counts, int n_nodes, int nbz,
    const float* __restrict__ Wq, const float* __restrict__ Wk,
    const float* __restrict__ Wv, unsigned short* __restrict__ WtB, int nbw,
    const float* __restrict__ We, const float* __restrict__ be,
    float* __restrict__ WeR, float* __restrict__ beR)
{
    const int bx = blockIdx.x;
    const int t  = threadIdx.x;
    if (bx < nbz) {                                   // zero counts
        const int i = bx * 256 + t;
        if (i < n_nodes) counts[i] = 0;
    } else if (bx < nbz + nbw) {                      // W[k][n] -> WtB[mat][n][k]
        const int idx = (bx - nbz) * 256 + t;
        const int mat = idx >> 14;
        const int rem = idx & 16383;
        const int n = rem >> 7, k = rem & 127;
        const float* W = (mat == 0) ? Wq : (mat == 1) ? Wk : Wv;
        WtB[mat * 16384 + n * 128 + k] = f2bf(W[k * 128 + n]);
    } else {                                          // We reduce
        const int k = t >> 3, h = t & 7;
        float s = 0.f;
#pragma unroll
        for (int d = 0; d < HEAD_DIM; ++d) s += We[k * OUT_DIM + h * HEAD_DIM + d];
        WeR[k * NUM_HEADS + h] = s;
        if (t < NUM_HEADS) {
            float sb = 0.f;
#pragma unroll
            for (int d = 0; d < HEAD_DIM; ++d) sb += be[t * HEAD_DIM + d];
            beR[t] = sb;
        }
    }
}

// ---------------------------------------------------------------------------
// megakernel: blocks [0,nbh) = edge prep (hist->rank + ebias, streaming);
//             blocks [nbh, nbh+3*nbq) = QKV bf16 MFMA.
// Independent work fused into one dispatch so the memory streams overlap.
// ---------------------------------------------------------------------------
__global__ __launch_bounds__(256) void mega_kernel(
    // edge part
    const int* __restrict__ el, int* __restrict__ counts, int* __restrict__ rank,
    const float* __restrict__ ef, const float* __restrict__ WeR,
    const float* __restrict__ beR, unsigned int* __restrict__ ebias_e,
    int n_edges, int nbh,
    // qkv part
    const float* __restrict__ X, const unsigned short* __restrict__ WtB,
    const float* __restrict__ bq, const float* __restrict__ bk,
    const float* __restrict__ bv,
    unsigned short* __restrict__ QVb, unsigned short* __restrict__ Kb,
    int n_nodes, int nbq)
{
    const int bx = blockIdx.x;
    const int t  = threadIdx.x;

    if (bx < nbh) {
        // ---------------- edge prep: hist (rank) + ebias ----------------
        __shared__ float WeRs[EDGE_DIM * NUM_HEADS];
        __shared__ float beRs[NUM_HEADS];
        WeRs[t] = WeR[t];
        if (t < NUM_HEADS) beRs[t] = beR[t];
        __syncthreads();

        const int e = bx * 256 + t;
        if (e >= n_edges) return;
        const int2 ed = ((const int2*)el)[e];
        rank[e] = atomicAdd(&counts[ed.y], 1);

        float acc[NUM_HEADS];
#pragma unroll
        for (int h = 0; h < NUM_HEADS; ++h) acc[h] = beRs[h];
        const f32x4* efr = (const f32x4*)(ef + (size_t)e * EDGE_DIM);
#pragma unroll
        for (int kk = 0; kk < 8; ++kk) {
            const f32x4 f = efr[kk];
            const float* w0 = &WeRs[(kk * 4 + 0) * NUM_HEADS];
            const float* w1 = &WeRs[(kk * 4 + 1) * NUM_HEADS];
            const float* w2 = &WeRs[(kk * 4 + 2) * NUM_HEADS];
            const float* w3 = &WeRs[(kk * 4 + 3) * NUM_HEADS];
#pragma unroll
            for (int h = 0; h < NUM_HEADS; ++h)
                acc[h] = fmaf(f[0], w0[h], fmaf(f[1], w1[h], fmaf(f[2], w2[h], fmaf(f[3], w3[h], acc[h]))));
        }
        u32x4 pk;
        pk[0] = (unsigned)f2bf(acc[0]) | ((unsigned)f2bf(acc[1]) << 16);
        pk[1] = (unsigned)f2bf(acc[2]) | ((unsigned)f2bf(acc[3]) << 16);
        pk[2] = (unsigned)f2bf(acc[4]) | ((unsigned)f2bf(acc[5]) << 16);
        pk[3] = (unsigned)f2bf(acc[6]) | ((unsigned)f2bf(acc[7]) << 16);
        *(u32x4*)(ebias_e + (size_t)e * 4) = pk;
    } else {
        // ---------------- QKV via bf16 MFMA ----------------
        __shared__ unsigned short stg[4][16][136];

        const int idx   = bx - nbh;
        const int which = idx / nbq;           // 0=Q, 1=K, 2=V
        const int mb    = idx - which * nbq;
        const float* bias = (which == 0) ? bq : (which == 1) ? bk : bv;
        const unsigned short* Wg = WtB + which * 16384;

        const int wave = t >> 6, lane = t & 63;
        const int quad = lane >> 4, li = lane & 15;
        const int m0 = mb * 64 + wave * 16;
        int mrow = m0 + li;
        if (mrow >= n_nodes) mrow = n_nodes - 1;

        f32x4 acc[8];
#pragma unroll
        for (int nt = 0; nt < 8; ++nt) acc[nt] = (f32x4){0.f, 0.f, 0.f, 0.f};

#pragma unroll
        for (int ks = 0; ks < 4; ++ks) {
            const f32x4* xr = (const f32x4*)(X + (size_t)mrow * 128 + ks * 32 + quad * 8);
            const f32x4 x0 = xr[0], x1 = xr[1];
            bf16x8 a;
            a[0] = (short)f2bf(x0[0]); a[1] = (short)f2bf(x0[1]);
            a[2] = (short)f2bf(x0[2]); a[3] = (short)f2bf(x0[3]);
            a[4] = (short)f2bf(x1[0]); a[5] = (short)f2bf(x1[1]);
            a[6] = (short)f2bf(x1[2]); a[7] = (short)f2bf(x1[3]);
#pragma unroll
            for (int nt = 0; nt < 8; ++nt) {
                const bf16x8 b = *(const bf16x8*)(Wg + (nt * 16 + li) * 128 + ks * 32 + quad * 8);
                acc[nt] = __builtin_amdgcn_mfma_f32_16x16x32_bf16(a, b, acc[nt], 0, 0, 0);
            }
        }

#pragma unroll
        for (int nt = 0; nt < 8; ++nt) {
            const float bb = bias[nt * 16 + li];
#pragma unroll
            for (int r = 0; r < 4; ++r)
                stg[wave][quad * 4 + r][nt * 16 + li] = f2bf(acc[nt][r] + bb);
        }
        __syncthreads();

        const int R = lane >> 2;
        const int c = lane & 3;
        const int node = m0 + R;
        if (node < n_nodes) {
            const u32x4* s = (const u32x4*)(&stg[wave][R][c * 32]);
            u32x4 d0 = s[0], d1 = s[1], d2 = s[2], d3 = s[3];
            unsigned short* dp =
                (which == 0) ? (QVb + (size_t)node * 256 + c * 32)
              : (which == 1) ? (Kb  + (size_t)node * 128 + c * 32)
              :                (QVb + (size_t)node * 256 + 128 + c * 32);
            u32x4* d = (u32x4*)dp;
            d[0] = d0; d[1] = d1; d[2] = d2; d[3] = d3;
        }
    }
}

// ---------------------------------------------------------------------------
// scan: phase 1 block sums; phase 2 fused into phase 3 (each block re-scans
// the <=256 block sums locally -- cheaper than a third launch).
// ---------------------------------------------------------------------------
__global__ __launch_bounds__(256) void scan1_kernel(
    const int* __restrict__ counts, int* __restrict__ bsums, int n)
{
    __shared__ int lds[256];
    const int i = blockIdx.x * 256 + threadIdx.x;
    lds[threadIdx.x] = (i < n) ? counts[i] : 0;
    __syncthreads();
    for (int off = 128; off > 0; off >>= 1) {
        if (threadIdx.x < off) lds[threadIdx.x] += lds[threadIdx.x + off];
        __syncthreads();
    }
    if (threadIdx.x == 0) bsums[blockIdx.x] = lds[0];
}

__global__ __launch_bounds__(256) void scan3_kernel(
    const int* __restrict__ counts, const int* __restrict__ bsums,
    int* __restrict__ offsets, int n, int n_edges, int nb)
{
    __shared__ int lds[256];
    const int t = threadIdx.x;

    // base for this block = exclusive prefix over bsums[0..bx)
    int v = (t < nb) ? bsums[t] : 0;
    lds[t] = v;
    __syncthreads();
    for (int off = 1; off < 256; off <<= 1) {
        const int u = (t >= off) ? lds[t - off] : 0;
        __syncthreads();
        lds[t] += u;
        __syncthreads();
    }
    const int base = (blockIdx.x > 0) ? lds[blockIdx.x - 1] : 0;
    __syncthreads();

    const int i = blockIdx.x * 256 + t;
    const int c = (i < n) ? counts[i] : 0;
    lds[t] = c;
    __syncthreads();
    for (int off = 1; off < 256; off <<= 1) {
        const int u = (t >= off) ? lds[t - off] : 0;
        __syncthreads();
        lds[t] += u;
        __syncthreads();
    }
    if (i < n) offsets[i] = base + lds[t] - c;
    if (blockIdx.x == 0 && t == 0) offsets[n] = n_edges;
}

// ---------------------------------------------------------------------------
// scatter: NO atomics. pos = offsets[dst] + rank[e]; one 32B record per edge
// [src:4 | pad:4 | ebias bf16 x8:16 | pad:8].
// ---------------------------------------------------------------------------
__global__ __launch_bounds__(256) void scatter_kernel(
    const int* __restrict__ el, const int* __restrict__ rank,
    const unsigned int* __restrict__ ebias_e,
    const int* __restrict__ offsets, unsigned int* __restrict__ recs,
    int n_edges)
{
    const int e = blockIdx.x * 256 + threadIdx.x;
    if (e >= n_edges) return;
    const int2 ed = ((const int2*)el)[e];
    const u32x4 eb = *(const u32x4*)(ebias_e + (size_t)e * 4);
    const int pos = offsets[ed.y] + rank[e];

    u32x4 r0, r1;
    r0[0] = (unsigned)ed.x;
    r0[1] = 0;
    r0[2] = eb[0];
    r0[3] = eb[1];
    r1[0] = eb[2];
    r1[1] = eb[3];
    r1[2] = 0; r1[3] = 0;
    u32x4* rp = (u32x4*)(recs + (size_t)pos * 8);
    rp[0] = r0;
    rp[1] = r1;
}

// ---------------------------------------------------------------------------
// aggregate: 2 edges per wave (32 lanes/edge, 4 elems/lane).
// record = 32B: src @ +0, ebias bf16[8] @ +8.
// ---------------------------------------------------------------------------
__global__ __launch_bounds__(256) void aggregate_kernel(
    const unsigned short* __restrict__ QVb, const unsigned short* __restrict__ Kb,
    const int* __restrict__ offsets, const unsigned int* __restrict__ recs,
    float* __restrict__ out, int n_nodes)
{
    const int gw   = (blockIdx.x * 256 + threadIdx.x) >> 6;
    const int lane = threadIdx.x & 63;
    const int half = lane >> 5, ln = lane & 31;
    const int node = gw * 2 + half;
    const int h = ln >> 2;
    const bool valid = node < n_nodes;

    int beg = 0, end = 0;
    if (valid) { beg = offsets[node]; end = offsets[node + 1]; }
    const int cnt = end - beg;
    const int mcnt = max(cnt, __shfl_xor(cnt, 32));

    float k0 = 0.f, k1 = 0.f, k2 = 0.f, k3 = 0.f;
    if (valid) {
        const uint2 kp = ((const uint2*)(Kb + (size_t)node * 128))[ln];
        k0 = bflo(kp.x); k1 = bfhi(kp.x); k2 = bflo(kp.y); k3 = bfhi(kp.y);
    }

    float a0 = 0.f, a1 = 0.f, a2 = 0.f, a3 = 0.f;

    uint2 qp = make_uint2(0, 0), vp = make_uint2(0, 0);
    float eb = 0.f;
    if (cnt > 0) {
        const unsigned int* rb = recs + (size_t)beg * 8;
        const int src = (int)rb[0];
        const unsigned int ebp = rb[2 + (h >> 1)];
        eb = (h & 1) ? bfhi(ebp) : bflo(ebp);
        const uint2* r = (const uint2*)(QVb + (size_t)src * 256);
        qp = r[ln];
        vp = r[32 + ln];
    }

    for (int i = 0; i < mcnt; ++i) {
        uint2 nqp = qp, nvp = vp;
        float neb = eb;
        if (i + 1 < cnt) {   // prefetch next edge (half-uniform branch)
            const unsigned int* rb = recs + (size_t)(beg + i + 1) * 8;
            const int ns = (int)rb[0];
            const unsigned int ebp = rb[2 + (h >> 1)];
            neb = (h & 1) ? bfhi(ebp) : bflo(ebp);
            const uint2* r = (const uint2*)(QVb + (size_t)ns * 256);
            nqp = r[ln];
            nvp = r[32 + ln];
        }

        const float q0 = bflo(qp.x), q1 = bfhi(qp.x);
        const float q2 = bflo(qp.y), q3 = bfhi(qp.y);
        float p = fmaf(q0, k0, fmaf(q1, k1, fmaf(q2, k2, q3 * k3)));
        p += __shfl_xor(p, 1);
        p += __shfl_xor(p, 2);
        const float score = fmaf(p, SCALE, eb);

        float mx = score;
        mx = fmaxf(mx, __shfl_xor(mx, 4));
        mx = fmaxf(mx, __shfl_xor(mx, 8));
        mx = fmaxf(mx, __shfl_xor(mx, 16));
        const float ex = __expf(score - mx);
        float den = ex;
        den += __shfl_xor(den, 4);
        den += __shfl_xor(den, 8);
        den += __shfl_xor(den, 16);
        const float w = __fdividef(ex, den);

        if (i < cnt) {
            a0 = fmaf(w, bflo(vp.x), a0);
            a1 = fmaf(w, bfhi(vp.x), a1);
            a2 = fmaf(w, bflo(vp.y), a2);
            a3 = fmaf(w, bfhi(vp.y), a3);
        }
        qp = nqp; vp = nvp; eb = neb;
    }

    if (valid) {
        f32x4 o; o[0] = a0; o[1] = a1; o[2] = a2; o[3] = a3;
        *(((f32x4*)(out + (size_t)node * OUT_DIM)) + ln) = o;
    }
}

// ---------------------------------------------------------------------------
extern "C" void kernel_launch(void* const* d_in, const int* in_sizes, int n_in,
                              void* d_out, int out_size, void* d_ws, size_t ws_size,
                              hipStream_t stream)
{
    const float* X   = (const float*)d_in[0];
    const float* ef  = (const float*)d_in[1];
    const float* Wq  = (const float*)d_in[2];
    const float* bq  = (const float*)d_in[3];
    const float* Wk  = (const float*)d_in[4];
    const float* bk  = (const float*)d_in[5];
    const float* Wv  = (const float*)d_in[6];
    const float* bv  = (const float*)d_in[7];
    const float* We  = (const float*)d_in[8];
    const float* be  = (const float*)d_in[9];
    const int*   el  = (const int*)d_in[10];

    const int n_nodes = in_sizes[0] / IN_DIM;
    const int n_edges = in_sizes[10] / 2;

    char* w = (char*)d_ws;
    auto alloc = [&](size_t bytes) { char* p = w; w += (bytes + 255) & ~(size_t)255; return p; };

    unsigned short* QVb    = (unsigned short*)alloc((size_t)n_nodes * 256 * 2);
    unsigned short* Kb     = (unsigned short*)alloc((size_t)n_nodes * 128 * 2);
    unsigned short* WtB    = (unsigned short*)alloc((size_t)3 * 128 * 128 * 2);
    unsigned int*   recs   = (unsigned int*)alloc((size_t)n_edges * 32);
    unsigned int*   ebias_e= (unsigned int*)alloc((size_t)n_edges * 16);
    int* rank    = (int*)alloc((size_t)n_edges * 4);
    float* WeR   = (float*)alloc(EDGE_DIM * NUM_HEADS * 4);
    float* beR   = (float*)alloc(NUM_HEADS * 4);
    int* counts  = (int*)alloc((size_t)n_nodes * 4);
    int* offsets = (int*)alloc((size_t)(n_nodes + 1) * 4);
    int* bsums   = (int*)alloc(256 * 4);

    const int nbz = (n_nodes + 255) / 256;          // 196
    const int nbw = (3 * 128 * 128) / 256;          // 192
    setup_kernel<<<nbz + nbw + 1, 256, 0, stream>>>(
        counts, n_nodes, nbz, Wq, Wk, Wv, WtB, nbw, We, be, WeR, beR);

    const int nbh = (n_edges + 255) / 256;          // 3125
    const int nbq = (n_nodes + 63) / 64;            // 782
    mega_kernel<<<nbh + 3 * nbq, 256, 0, stream>>>(
        el, counts, rank, ef, WeR, beR, ebias_e, n_edges, nbh,
        X, WtB, bq, bk, bv, QVb, Kb, n_nodes, nbq);

    const int nb = (n_nodes + 255) / 256;           // 196
    scan1_kernel<<<nb, 256, 0, stream>>>(counts, bsums, n_nodes);
    scan3_kernel<<<nb, 256, 0, stream>>>(counts, bsums, offsets, n_nodes, n_edges, nb);

    scatter_kernel<<<(n_edges + 255) / 256, 256, 0, stream>>>(
        el, rank, ebias_e, offsets, recs, n_edges);

    const int nwaves = (n_nodes + 1) / 2;
    aggregate_kernel<<<(nwaves * 64 + 255) / 256, 256, 0, stream>>>(
        QVb, Kb, offsets, recs, (float*)d_out, n_nodes);
}